// Round 3
// baseline (495.782 us; speedup 1.0000x reference)
//
#include <hip/hip_runtime.h>
#include <math.h>

#define NB 8
#define CDIM 256
#define HWD 1024
#define NH 8
#define HD 32
#define NN 102
#define GD 64

typedef __attribute__((ext_vector_type(8))) short bf16x8;
typedef __attribute__((ext_vector_type(4))) short bf16x4;
typedef __attribute__((ext_vector_type(4))) float f32x4;

__device__ inline short f2bf(float f) {
  union { float f; unsigned u; } v; v.f = f;
  unsigned r = v.u + 0x7fffu + ((v.u >> 16) & 1u);
  return (short)(r >> 16);
}
__device__ inline float bf2f(short s) {
  union { unsigned u; float f; } v;
  v.u = ((unsigned)(unsigned short)s) << 16;
  return v.f;
}

// ---------------- weight transpose (32x32 LDS tiles) ----------------
__global__ __launch_bounds__(256) void transpose_k(const float* __restrict__ in,
                                                   float* __restrict__ out, int R, int C) {
  __shared__ float tile[32][33];
  int c0 = blockIdx.x * 32, r0 = blockIdx.y * 32;
  for (int i = threadIdx.y; i < 32; i += 8) {
    int r = r0 + i, c = c0 + threadIdx.x;
    if (r < R && c < C) tile[i][threadIdx.x] = in[r * C + c];
  }
  __syncthreads();
  for (int i = threadIdx.y; i < 32; i += 8) {
    int c = c0 + i, r = r0 + threadIdx.x;
    if (r < R && c < C) out[c * R + r] = tile[threadIdx.x][i];
  }
}

// ---------------- importance = unbiased variance over channels (wide grid) ----------------
__global__ __launch_bounds__(256) void importance_k(const float* __restrict__ x,
                                                    float* __restrict__ imp) {
  __shared__ float red[8][33];
  int bp = blockIdx.x;                       // 256 blocks: b = bp>>5, 32 positions each
  int b = bp >> 5, p0 = (bp & 31) << 5;
  int t = threadIdx.x;
  int pl = t & 31, cg = t >> 5;
  const float* xp = x + (size_t)b * CDIM * HWD + p0 + pl;
  float s = 0.f;
  for (int cc = 0; cc < 32; ++cc) s += xp[(size_t)(cg * 32 + cc) * HWD];
  red[cg][pl] = s;
  __syncthreads();
  float tot = 0.f;
  for (int g = 0; g < 8; ++g) tot += red[g][pl];
  float mean = tot * (1.f / CDIM);
  __syncthreads();
  float v = 0.f;
  for (int cc = 0; cc < 32; ++cc) {
    float d = xp[(size_t)(cg * 32 + cc) * HWD] - mean;
    v += d * d;
  }
  red[cg][pl] = v;
  __syncthreads();
  if (t < 32) {
    float vv = 0.f;
    for (int g = 0; g < 8; ++g) vv += red[g][t];
    imp[b * 1024 + p0 + t] = vv * (1.f / (CDIM - 1));
  }
}

// ---------------- fused graph pipeline: topk -> feats -> adj(sim) -> GAT x2 -> gate ----------------
struct TK { float sv[1024]; int si[1024]; };
union RB { TK tk; unsigned char adjL[NN * NN]; };
struct GL { float h0[NN * 65]; float g0[NN * 65]; };
union RA { short fnb[NN * 260]; GL gl; };

__global__ __launch_bounds__(1024) void graph_k(
    const float* __restrict__ x, const float* __restrict__ imp,
    const float* __restrict__ g0W, const float* __restrict__ g0as,
    const float* __restrict__ g0ad, const float* __restrict__ g0b,
    const float* __restrict__ g1W, const float* __restrict__ g1as,
    const float* __restrict__ g1ad, const float* __restrict__ g1b,
    const float* __restrict__ wg2a, const float* __restrict__ bg2a,
    int* __restrict__ topi, int* __restrict__ nodeof,
    float* __restrict__ feats, unsigned char* __restrict__ adj,
    float* __restrict__ gwb) {
  __shared__ RB rb;
  __shared__ RA ra;
  __shared__ float rnL[NN];
  __shared__ int topiL[NN];
  __shared__ float asrcL[104], adstL[104];
  int b = blockIdx.x, t = threadIdx.x;
  int wv = t >> 6, lane = t & 63;

  // ---- phase T: top-102 bitonic sort ----
  rb.tk.sv[t] = imp[b * 1024 + t];
  rb.tk.si[t] = t;
  nodeof[b * 1024 + t] = -1;
  __syncthreads();
  for (int k = 2; k <= 1024; k <<= 1) {
    for (int j = k >> 1; j > 0; j >>= 1) {
      int ixj = t ^ j;
      if (ixj > t) {
        bool up = ((t & k) == 0);
        float a = rb.tk.sv[t], c = rb.tk.sv[ixj];
        if ((a > c) == up) {
          rb.tk.sv[t] = c; rb.tk.sv[ixj] = a;
          int ti = rb.tk.si[t]; rb.tk.si[t] = rb.tk.si[ixj]; rb.tk.si[ixj] = ti;
        }
      }
      __syncthreads();
    }
  }
  if (t >= 1024 - NN) {
    int n = 1023 - t;
    int idx = rb.tk.si[t];
    topi[b * 128 + n] = idx;
    topiL[n] = idx;
    nodeof[b * 1024 + idx] = n;
  }
  __syncthreads();

  // ---- phase F: gather feats (fp32 -> global), sumsq -> rn, fnb bf16 ----
  {
    int n = t >> 3, cg = t & 7;
    if (n < NN) {
      int idx = topiL[n];
      const float* xb = x + (size_t)b * CDIM * HWD + idx;
      float ssl = 0.f;
      for (int cc = 0; cc < 32; ++cc) {
        int c = cg * 32 + cc;
        float v = xb[(size_t)c * HWD];
        feats[((size_t)b * NN + n) * CDIM + c] = v;
        ra.fnb[n * 260 + c] = f2bf(v);
        ssl += v * v;
      }
      ssl += __shfl_xor(ssl, 1);
      ssl += __shfl_xor(ssl, 2);
      ssl += __shfl_xor(ssl, 4);
      if (cg == 0) rnL[n] = 1.f / fmaxf(sqrtf(ssl), 1e-12f);
    }
  }
  __syncthreads();
  // normalize fnb in place
  for (int e = t; e < NN * 256; e += 1024) {
    int n2 = e >> 8, c = e & 255;
    ra.fnb[n2 * 260 + c] = f2bf(bf2f(ra.fnb[n2 * 260 + c]) * rnL[n2]);
  }
  __syncthreads();

  // ---- phase S: cosine sim via bf16 MFMA -> adjL (self-loops via diag sim ~ 1) ----
  {
    int quad = lane >> 4, l16 = lane & 15;
    for (int tid = wv; tid < 49; tid += 16) {
      int I = tid / 7, J = tid % 7;
      int rA = I * 16 + l16; if (rA > NN - 1) rA = NN - 1;
      int rBr = J * 16 + l16; if (rBr > NN - 1) rBr = NN - 1;
      f32x4 acc = (f32x4){0.f, 0.f, 0.f, 0.f};
      for (int kb = 0; kb < 8; ++kb) {
        int oa = rA * 260 + kb * 32 + quad * 8;
        int ob = rBr * 260 + kb * 32 + quad * 8;
        bf16x4 a0 = *(const bf16x4*)&ra.fnb[oa];
        bf16x4 a1 = *(const bf16x4*)&ra.fnb[oa + 4];
        bf16x4 b0 = *(const bf16x4*)&ra.fnb[ob];
        bf16x4 b1 = *(const bf16x4*)&ra.fnb[ob + 4];
        bf16x8 af = (bf16x8){a0.x, a0.y, a0.z, a0.w, a1.x, a1.y, a1.z, a1.w};
        bf16x8 bf = (bf16x8){b0.x, b0.y, b0.z, b0.w, b1.x, b1.y, b1.z, b1.w};
        acc = __builtin_amdgcn_mfma_f32_16x16x32_bf16(af, bf, acc, 0, 0, 0);
      }
#pragma unroll
      for (int r = 0; r < 4; ++r) {
        int i = I * 16 + quad * 4 + r, j = J * 16 + l16;
        if (i < NN && j < NN)
          rb.adjL[i * NN + j] = (acc[r] > 0.6f || i == j) ? 1 : 0;
      }
    }
  }
  __syncthreads();
  // adj -> global (needed by attention)
  for (int e = t; e < NN * NN; e += 1024) {
    int i = e / NN, j = e - i * NN;
    adj[((size_t)b * NN + i) * NN + j] = rb.adjL[i * NN + j];
  }

  // ---- phase G0: h0 = feats @ W0 (fp32), asrc/adst ----
  for (int n = wv; n < NN; n += 16) {
    const float* fp = feats + ((size_t)b * NN + n) * CDIM;
    float acc = 0.f;
    for (int c = 0; c < CDIM; ++c) acc += fp[c] * g0W[c * GD + lane];
    ra.gl.h0[n * 65 + lane] = acc;
    float s1 = acc * g0as[lane], s2 = acc * g0ad[lane];
    for (int m = 1; m < 64; m <<= 1) { s1 += __shfl_xor(s1, m); s2 += __shfl_xor(s2, m); }
    if (lane == 0) { asrcL[n] = s1; adstL[n] = s2; }
  }
  __syncthreads();

  // ---- phase G0soft: masked softmax + aggregate + bias + relu -> g0 ----
  for (int i = wv; i < NN; i += 16) {
    float adsti = adstL[i];
    float p0 = 0.f, p1 = 0.f;
    if (rb.adjL[i * NN + lane]) {
      float z = adsti + asrcL[lane];
      p0 = __expf(z > 0.f ? z : 0.2f * z);
    }
    int j1 = 64 + lane;
    if (j1 < NN && rb.adjL[i * NN + j1]) {
      float z = adsti + asrcL[j1];
      p1 = __expf(z > 0.f ? z : 0.2f * z);
    }
    float s = p0 + p1;
    for (int m = 1; m < 64; m <<= 1) s += __shfl_xor(s, m);
    float inv = 1.f / s;
    float o = 0.f;
    for (int j = 0; j < 64; ++j)
      o += __shfl(p0, j) * ra.gl.h0[j * 65 + lane];
    for (int j = 64; j < NN; ++j)
      o += __shfl(p1, j - 64) * ra.gl.h0[j * 65 + lane];
    o = o * inv + g0b[lane];
    ra.gl.g0[i * 65 + lane] = fmaxf(o, 0.f);
  }
  __syncthreads();

  // ---- phase G1: h1 = g0 @ W1 (overwrites h0 slot), asrc1/adst1 ----
  for (int n = wv; n < NN; n += 16) {
    float acc = 0.f;
    for (int c = 0; c < GD; ++c) acc += ra.gl.g0[n * 65 + c] * g1W[c * GD + lane];
    float s1 = acc * g1as[lane], s2 = acc * g1ad[lane];
    for (int m = 1; m < 64; m <<= 1) { s1 += __shfl_xor(s1, m); s2 += __shfl_xor(s2, m); }
    ra.gl.h0[n * 65 + lane] = acc;
    if (lane == 0) { asrcL[n] = s1; adstL[n] = s2; }
  }
  __syncthreads();

  // ---- phase G1soft -> g1 (overwrites g0 slot) ----
  for (int i = wv; i < NN; i += 16) {
    float adsti = adstL[i];
    float p0 = 0.f, p1 = 0.f;
    if (rb.adjL[i * NN + lane]) {
      float z = adsti + asrcL[lane];
      p0 = __expf(z > 0.f ? z : 0.2f * z);
    }
    int j1 = 64 + lane;
    if (j1 < NN && rb.adjL[i * NN + j1]) {
      float z = adsti + asrcL[j1];
      p1 = __expf(z > 0.f ? z : 0.2f * z);
    }
    float s = p0 + p1;
    for (int m = 1; m < 64; m <<= 1) s += __shfl_xor(s, m);
    float inv = 1.f / s;
    float o = 0.f;
    for (int j = 0; j < 64; ++j)
      o += __shfl(p0, j) * ra.gl.h0[j * 65 + lane];
    for (int j = 64; j < NN; ++j)
      o += __shfl(p1, j - 64) * ra.gl.h0[j * 65 + lane];
    o = o * inv + g1b[lane];
    ra.gl.g0[i * 65 + lane] = fmaxf(o, 0.f);
  }
  __syncthreads();

  // ---- phase G2A: gw = sigmoid(g1 @ wg2a^T + b) ----
  if (t < NN * NH) {
    int n = t >> 3, hh = t & 7;
    float z = bg2a[hh];
    for (int c = 0; c < GD; ++c) z += ra.gl.g0[n * 65 + c] * wg2a[hh * GD + c];
    gwb[((size_t)b * NN + n) * NH + hh] = 1.f / (1.f + __expf(-z));
  }
}

#define FMA16(acc, av, bv)                                                            \
  acc[0][0] += av.x * bv.x; acc[0][1] += av.x * bv.y; acc[0][2] += av.x * bv.z;       \
  acc[0][3] += av.x * bv.w;                                                           \
  acc[1][0] += av.y * bv.x; acc[1][1] += av.y * bv.y; acc[1][2] += av.y * bv.z;       \
  acc[1][3] += av.y * bv.w;                                                           \
  acc[2][0] += av.z * bv.x; acc[2][1] += av.z * bv.y; acc[2][2] += av.z * bv.z;       \
  acc[2][3] += av.z * bv.w;                                                           \
  acc[3][0] += av.w * bv.x; acc[3][1] += av.w * bv.y; acc[3][2] += av.w * bv.z;       \
  acc[3][3] += av.w * bv.w;

// ---------------- QKV GEMM: emits split-bf16 Q/K ([bh][p][32] hi+lo) and V^T bf16 [bh][32][1024] ----------------
__global__ __launch_bounds__(256) void qkv_k(const float* __restrict__ x,
                                             const float* __restrict__ wT,
                                             short* __restrict__ qhp, short* __restrict__ qlp,
                                             short* __restrict__ khp, short* __restrict__ klp,
                                             short* __restrict__ vtp) {
  __shared__ float a_s[16][68];
  __shared__ float b_s[16][68];
  __shared__ float c_s[64][68];
  int m0 = blockIdx.x * 64, n0 = blockIdx.y * 64;
  int b = m0 >> 10, p0 = m0 & 1023;
  int t = threadIdx.x, tx = t & 15, ty = t >> 4;
  float acc[4][4] = {};
  for (int k0 = 0; k0 < 256; k0 += 16) {
    int m = t & 63, kb = t >> 6;
#pragma unroll
    for (int r = 0; r < 4; ++r) {
      int kk = kb * 4 + r;
      a_s[kk][m] = x[((size_t)b * 256 + k0 + kk) * 1024 + p0 + m];
      b_s[kk][m] = wT[(k0 + kk) * 768 + n0 + m];
    }
    __syncthreads();
#pragma unroll
    for (int kk = 0; kk < 16; ++kk) {
      float4 av = *(const float4*)&a_s[kk][ty * 4];
      float4 bv = *(const float4*)&b_s[kk][tx * 4];
      FMA16(acc, av, bv)
    }
    __syncthreads();
  }
  int qi = n0 >> 8;
  if (qi < 2) {
    const float scale = (qi == 0) ? 0.17677669529663687f : 1.f;
    short* hp = (qi == 0) ? qhp : khp;
    short* lp = (qi == 0) ? qlp : klp;
    int n = n0 + tx * 4;
    int hh = (n >> 5) & 7, d = n & 31;
#pragma unroll
    for (int i = 0; i < 4; ++i) {
      int p = p0 + ty * 4 + i;
      size_t e = ((size_t)(b * 8 + hh) * 1024 + p) * 32 + d;
      float v0 = acc[i][0] * scale, v1 = acc[i][1] * scale;
      float v2 = acc[i][2] * scale, v3 = acc[i][3] * scale;
      short4 hi, lo;
      hi.x = f2bf(v0); lo.x = f2bf(v0 - bf2f(hi.x));
      hi.y = f2bf(v1); lo.y = f2bf(v1 - bf2f(hi.y));
      hi.z = f2bf(v2); lo.z = f2bf(v2 - bf2f(hi.z));
      hi.w = f2bf(v3); lo.w = f2bf(v3 - bf2f(hi.w));
      *(short4*)(hp + e) = hi;
      *(short4*)(lp + e) = lo;
    }
  } else {
    // V block: transpose 64p x 64n via LDS, emit Vt[bh][d][p] bf16
#pragma unroll
    for (int i = 0; i < 4; ++i)
      *(float4*)&c_s[ty * 4 + i][tx * 4] = *(float4*)&acc[i][0];
    __syncthreads();
    int dl = t >> 2, pg = t & 3;
    int n = n0 + dl;
    int hh = (n >> 5) & 7, d = n & 31;
    size_t rowb = (size_t)(b * 8 + hh) * 32768 + (size_t)d * 1024 + p0;
#pragma unroll
    for (int r = 0; r < 4; ++r) {
      int pl = pg * 16 + r * 4;
      short4 s4;
      s4.x = f2bf(c_s[pl + 0][dl]);
      s4.y = f2bf(c_s[pl + 1][dl]);
      s4.z = f2bf(c_s[pl + 2][dl]);
      s4.w = f2bf(c_s[pl + 3][dl]);
      *(short4*)(vtp + rowb + pl) = s4;
    }
  }
}

// ---------------- flash attention v2: 16 q-rows/wave, deferred-sum softmax (no max, no shuffles in loop) ----------------
__global__ __launch_bounds__(256, 4) void attn_k(const short* __restrict__ qh,
                                                 const short* __restrict__ ql,
                                                 const short* __restrict__ kh,
                                                 const short* __restrict__ kl,
                                                 const short* __restrict__ vt,
                                                 const int* __restrict__ nodeof,
                                                 const float* __restrict__ gw,
                                                 const unsigned char* __restrict__ adj,
                                                 float* __restrict__ ao) {
  __shared__ __align__(16) short p_s[4][16 * 72];  // per-wave P (16x64, ld=72) / overlay O f32 (16x36)
  __shared__ float aw_s[4][16];
  int t = threadIdx.x;
  int wid = t >> 6, lane = t & 63, quad = lane >> 4, l16 = lane & 15;
  int bh = blockIdx.y, b = bh >> 3, h = bh & 7;
  int q0 = blockIdx.x * 64 + wid * 16;
  size_t base = (size_t)bh * 32768;
  short* pw = &p_s[wid][0];
  float* aw = &aw_s[wid][0];

  size_t qoff = base + (size_t)(q0 + l16) * 32 + quad * 8;
  bf16x8 qhf = *(const bf16x8*)(qh + qoff);
  bf16x8 qlf = *(const bf16x8*)(ql + qoff);

  int irow[4]; float grq[4];
#pragma unroll
  for (int r = 0; r < 4; ++r) {
    int qr = q0 + quad * 4 + r;
    int in_ = nodeof[b * 1024 + qr];
    irow[r] = in_;
    grq[r] = (in_ >= 0) ? gw[((size_t)b * NN + in_) * NH + h] : 0.f;
  }
  const unsigned char* adjB = adj + (size_t)b * NN * NN;

  f32x4 ot[2];
  ot[0] = (f32x4){0.f, 0.f, 0.f, 0.f};
  ot[1] = (f32x4){0.f, 0.f, 0.f, 0.f};
  float l_r[4] = {0.f, 0.f, 0.f, 0.f};

  for (int ch = 0; ch < 16; ++ch) {
    int c0 = ch * 64;
    bf16x8 khf[4], klf[4];
#pragma unroll
    for (int ni = 0; ni < 4; ++ni) {
      size_t off = base + (size_t)(c0 + ni * 16 + l16) * 32 + quad * 8;
      khf[ni] = *(const bf16x8*)(kh + off);
      klf[ni] = *(const bf16x8*)(kl + off);
    }
    bf16x8 vaf[2][2];
#pragma unroll
    for (int mi = 0; mi < 2; ++mi)
#pragma unroll
      for (int ks = 0; ks < 2; ++ks)
        vaf[mi][ks] = *(const bf16x8*)(vt + base + (size_t)(mi * 16 + l16) * 1024 +
                                       c0 + ks * 32 + quad * 8);
    int jn[4]; float gcn[4];
#pragma unroll
    for (int ni = 0; ni < 4; ++ni) {
      int j = nodeof[b * 1024 + c0 + ni * 16 + l16];
      jn[ni] = j;
      gcn[ni] = (j >= 0) ? gw[((size_t)b * NN + j) * NH + h] : 0.f;
    }
    // S = Q K^T, split-bf16 (drop Ql*Kl, ~2^-16 relative)
    f32x4 s[4];
#pragma unroll
    for (int ni = 0; ni < 4; ++ni) {
      f32x4 a = (f32x4){0.f, 0.f, 0.f, 0.f};
      a = __builtin_amdgcn_mfma_f32_16x16x32_bf16(qhf, khf[ni], a, 0, 0, 0);
      a = __builtin_amdgcn_mfma_f32_16x16x32_bf16(qhf, klf[ni], a, 0, 0, 0);
      a = __builtin_amdgcn_mfma_f32_16x16x32_bf16(qlf, khf[ni], a, 0, 0, 0);
      s[ni] = a;
    }
    // graph modulation (scale folded into Q upstream)
#pragma unroll
    for (int r = 0; r < 4; ++r) {
      int in_ = irow[r];
      if (in_ >= 0) {
        const unsigned char* ar = adjB + (size_t)in_ * NN;
        float g = grq[r];
#pragma unroll
        for (int ni = 0; ni < 4; ++ni)
          if (jn[ni] >= 0 && ar[jn[ni]]) s[ni][r] += g * gcn[ni];
      }
    }
    // deferred-sum softmax: p = exp(s) (bounded scores, no overflow), accumulate partial l
#pragma unroll
    for (int r = 0; r < 4; ++r) {
      float e0 = __expf(s[0][r]);
      float e1 = __expf(s[1][r]);
      float e2 = __expf(s[2][r]);
      float e3 = __expf(s[3][r]);
      l_r[r] += (e0 + e1) + (e2 + e3);
      int prow = (quad * 4 + r) * 72;
      pw[prow + 0 + l16] = f2bf(e0);
      pw[prow + 16 + l16] = f2bf(e1);
      pw[prow + 32 + l16] = f2bf(e2);
      pw[prow + 48 + l16] = f2bf(e3);
    }
    // O^T += V^T P^T  (per-wave LDS, wave-internal DS ordering, no barriers)
#pragma unroll
    for (int ks = 0; ks < 2; ++ks) {
      bf16x8 pb = *(const bf16x8*)(pw + l16 * 72 + ks * 32 + quad * 8);
      ot[0] = __builtin_amdgcn_mfma_f32_16x16x32_bf16(vaf[0][ks], pb, ot[0], 0, 0, 0);
      ot[1] = __builtin_amdgcn_mfma_f32_16x16x32_bf16(vaf[1][ks], pb, ot[1], 0, 0, 0);
    }
  }
  // final row-sum reduce (once), invert, scale, transpose via per-wave LDS, store
#pragma unroll
  for (int r = 0; r < 4; ++r) {
    float ls = l_r[r];
    ls += __shfl_xor(ls, 1);
    ls += __shfl_xor(ls, 2);
    ls += __shfl_xor(ls, 4);
    ls += __shfl_xor(ls, 8);
    if (l16 == 0) aw[quad * 4 + r] = 1.f / ls;
  }
  float li = aw[l16];
  ot[0] *= li;
  ot[1] *= li;
  float* os = (float*)pw;
#pragma unroll
  for (int mi = 0; mi < 2; ++mi)
#pragma unroll
    for (int r = 0; r < 4; ++r)
      os[l16 * 36 + mi * 16 + quad * 4 + r] = ot[mi][r];
  int qr2 = lane >> 2, dg = (lane & 3) * 8;
  size_t ob = (size_t)(b * 1024 + q0 + qr2) * 256 + h * 32 + dg;
  *(float4*)&ao[ob] = *(float4*)&os[qr2 * 36 + dg];
  *(float4*)&ao[ob + 4] = *(float4*)&os[qr2 * 36 + dg + 4];
}

// ---------------- proj GEMM + bias + transposed store ----------------
__global__ __launch_bounds__(256) void proj_k(const float* __restrict__ ao,
                                              const float* __restrict__ wT,
                                              const float* __restrict__ bias,
                                              float* __restrict__ out) {
  __shared__ float a_s[16][68];
  __shared__ float b_s[16][68];
  __shared__ float c_s[64][68];
  int m0 = blockIdx.x * 64, n0 = blockIdx.y * 64;
  int b = m0 >> 10, p0 = m0 & 1023;
  int t = threadIdx.x, tx = t & 15, ty = t >> 4;
  float acc[4][4] = {};
  for (int k0 = 0; k0 < 256; k0 += 16) {
    {
      int kk = t & 15, mm = t >> 4;
#pragma unroll
      for (int r = 0; r < 4; ++r) {
        int m = mm + r * 16;
        a_s[kk][m] = ao[(size_t)(m0 + m) * 256 + k0 + kk];
      }
      int mB = t & 63, kb = t >> 6;
#pragma unroll
      for (int r2 = 0; r2 < 4; ++r2) {
        int kk2 = kb * 4 + r2;
        b_s[kk2][mB] = wT[(k0 + kk2) * 256 + n0 + mB];
      }
    }
    __syncthreads();
#pragma unroll
    for (int kk = 0; kk < 16; ++kk) {
      float4 av = *(const float4*)&a_s[kk][ty * 4];
      float4 bv = *(const float4*)&b_s[kk][tx * 4];
      FMA16(acc, av, bv)
    }
    __syncthreads();
  }
#pragma unroll
  for (int i = 0; i < 4; ++i)
#pragma unroll
    for (int j = 0; j < 4; ++j) c_s[tx * 4 + j][ty * 4 + i] = acc[i][j];
  __syncthreads();
  {
    int cl = t >> 2, pg = t & 3;
    float bv = bias[n0 + cl];
#pragma unroll
    for (int r = 0; r < 4; ++r) {
      int p = pg * 16 + r * 4;
      float4 v4 = {c_s[cl][p] + bv, c_s[cl][p + 1] + bv, c_s[cl][p + 2] + bv, c_s[cl][p + 3] + bv};
      *(float4*)&out[((size_t)b * 256 + n0 + cl) * 1024 + p0 + p] = v4;
    }
  }
}

extern "C" void kernel_launch(void* const* d_in, const int* in_sizes, int n_in,
                              void* d_out, int out_size, void* d_ws, size_t ws_size,
                              hipStream_t stream) {
  const float* x      = (const float*)d_in[0];
  const float* w_qkv  = (const float*)d_in[1];
  const float* w_proj = (const float*)d_in[2];
  const float* b_proj = (const float*)d_in[3];
  const float* g0W    = (const float*)d_in[4];
  const float* g0as   = (const float*)d_in[5];
  const float* g0ad   = (const float*)d_in[6];
  const float* g0b    = (const float*)d_in[7];
  const float* g1W    = (const float*)d_in[8];
  const float* g1as   = (const float*)d_in[9];
  const float* g1ad   = (const float*)d_in[10];
  const float* g1b    = (const float*)d_in[11];
  const float* wg2a   = (const float*)d_in[12];
  const float* bg2a   = (const float*)d_in[13];
  float* out = (float*)d_out;
  float* ws = (float*)d_ws;

  size_t o = 0;
  auto alloc = [&](size_t nf) { float* p = ws + o; o += (nf + 15) & ~(size_t)15; return p; };
  float* wqkvT  = alloc(256 * 768);
  float* wprojT = alloc(256 * 256);
  float* imp    = alloc(8 * 1024);
  int*   topi   = (int*)alloc(8 * 128);
  int*   nodeof = (int*)alloc(8 * 1024);
  float* feats  = alloc(8 * NN * 256);
  unsigned char* adj = (unsigned char*)alloc((8 * NN * NN + 3) / 4 + 16);
  float* gwb    = alloc(8 * NN * 8);
  short* qh     = (short*)alloc(1048576);
  short* ql     = (short*)alloc(1048576);
  short* kh     = (short*)alloc(1048576);
  short* kl     = (short*)alloc(1048576);
  short* vt     = (short*)alloc(1048576);
  float* ao     = alloc((size_t)8 * 1024 * 256);
  if (ws_size < o * sizeof(float)) return;

  transpose_k<<<dim3(8, 24), dim3(32, 8), 0, stream>>>(w_qkv, wqkvT, 768, 256);
  transpose_k<<<dim3(8, 8), dim3(32, 8), 0, stream>>>(w_proj, wprojT, 256, 256);
  importance_k<<<256, 256, 0, stream>>>(x, imp);
  graph_k<<<8, 1024, 0, stream>>>(x, imp, g0W, g0as, g0ad, g0b, g1W, g1as, g1ad, g1b,
                                  wg2a, bg2a, topi, nodeof, feats, adj, gwb);
  qkv_k<<<dim3(128, 12), 256, 0, stream>>>(x, wqkvT, qh, ql, kh, kl, vt);
  attn_k<<<dim3(16, 64), 256, 0, stream>>>(qh, ql, kh, kl, vt, nodeof, gwb, adj, ao);
  proj_k<<<dim3(128, 4), 256, 0, stream>>>(ao, wprojT, b_proj, out);
}

// Round 4
// 349.115 us; speedup vs baseline: 1.4201x; 1.4201x over previous
//
#include <hip/hip_runtime.h>
#include <math.h>

#define NB 8
#define CDIM 256
#define HWD 1024
#define NH 8
#define HD 32
#define NN 102
#define GD 64

typedef __attribute__((ext_vector_type(8))) short bf16x8;
typedef __attribute__((ext_vector_type(4))) float f32x4;

__device__ inline short f2bf(float f) {
  union { float f; unsigned u; } v; v.f = f;
  unsigned r = v.u + 0x7fffu + ((v.u >> 16) & 1u);
  return (short)(r >> 16);
}
__device__ inline float bf2f(short s) {
  union { unsigned u; float f; } v;
  v.u = ((unsigned)(unsigned short)s) << 16;
  return v.f;
}

// ---------------- weight transpose (32x32 LDS tiles) ----------------
__global__ __launch_bounds__(256) void transpose_k(const float* __restrict__ in,
                                                   float* __restrict__ out, int R, int C) {
  __shared__ float tile[32][33];
  int c0 = blockIdx.x * 32, r0 = blockIdx.y * 32;
  for (int i = threadIdx.y; i < 32; i += 8) {
    int r = r0 + i, c = c0 + threadIdx.x;
    if (r < R && c < C) tile[i][threadIdx.x] = in[r * C + c];
  }
  __syncthreads();
  for (int i = threadIdx.y; i < 32; i += 8) {
    int c = c0 + i, r = r0 + threadIdx.x;
    if (r < R && c < C) out[c * R + r] = tile[threadIdx.x][i];
  }
}

// ---------------- prep: bf16-transposed GAT weights ----------------
__global__ __launch_bounds__(256) void prep_k(const float* __restrict__ g0W,
                                              const float* __restrict__ g1W,
                                              short* __restrict__ w0bT,
                                              short* __restrict__ w1bT) {
  int t = blockIdx.x * 256 + threadIdx.x;     // 80 blocks -> 20480 threads
  if (t < 16384) {
    int c = t >> 6, f = t & 63;
    w0bT[f * 256 + c] = f2bf(g0W[t]);
  } else if (t < 20480) {
    int u2 = t - 16384;
    int c = u2 >> 6, f = u2 & 63;
    w1bT[f * 64 + c] = f2bf(g1W[u2]);
  }
}

// ---------------- importance = unbiased variance over channels ----------------
__global__ __launch_bounds__(256) void importance_k(const float* __restrict__ x,
                                                    float* __restrict__ imp) {
  __shared__ float red[8][33];
  int bp = blockIdx.x;
  int b = bp >> 5, p0 = (bp & 31) << 5;
  int t = threadIdx.x;
  int pl = t & 31, cg = t >> 5;
  const float* xp = x + (size_t)b * CDIM * HWD + p0 + pl;
  float s = 0.f;
  for (int cc = 0; cc < 32; ++cc) s += xp[(size_t)(cg * 32 + cc) * HWD];
  red[cg][pl] = s;
  __syncthreads();
  float tot = 0.f;
  for (int g = 0; g < 8; ++g) tot += red[g][pl];
  float mean = tot * (1.f / CDIM);
  __syncthreads();
  float v = 0.f;
  for (int cc = 0; cc < 32; ++cc) {
    float d = xp[(size_t)(cg * 32 + cc) * HWD] - mean;
    v += d * d;
  }
  red[cg][pl] = v;
  __syncthreads();
  if (t < 32) {
    float vv = 0.f;
    for (int g = 0; g < 8; ++g) vv += red[g][t];
    imp[b * 1024 + p0 + t] = vv * (1.f / (CDIM - 1));
  }
}

// ---------------- fused graph pipeline v2: MFMA GAT ----------------
union GraphLDS {
  struct { float sv[1024]; int si[1024]; } tk;        // sort scratch (8 KB)
  struct {
    short h0T[64 * 136];      // [f][j] bf16, j-pad zeroed 102..135 (17408 B)
    short alphaB[102 * 136];  // [i][j] bf16 softmax rows (27744 B)
    short gB[102 * 72];       // [i][f] bf16 layer output (14688 B)
  } m;
};

__global__ __launch_bounds__(1024) void graph_k(
    const float* __restrict__ x, const float* __restrict__ imp,
    const short* __restrict__ w0bT, const short* __restrict__ w1bT,
    const float* __restrict__ g0as, const float* __restrict__ g0ad,
    const float* __restrict__ g0b,
    const float* __restrict__ g1as, const float* __restrict__ g1ad,
    const float* __restrict__ g1b,
    const float* __restrict__ wg2a, const float* __restrict__ bg2a,
    int* __restrict__ nodeof, short* __restrict__ fnG,
    unsigned char* __restrict__ adjG, float* __restrict__ gwb) {
  __shared__ GraphLDS u;
  __shared__ ushort adjPack[NN][8];     // 128-bit adjacency rows
  __shared__ float normL[NN];
  __shared__ float asrcL[NN], adstL[NN];
  __shared__ int topiL[NN];
  int b = blockIdx.x, t = threadIdx.x;
  int wv = t >> 6, lane = t & 63, quad = lane >> 4, l16 = lane & 15;

  // ---- phase T: top-102 bitonic sort ----
  u.tk.sv[t] = imp[b * 1024 + t];
  u.tk.si[t] = t;
  nodeof[b * 1024 + t] = -1;
  __syncthreads();
  for (int k = 2; k <= 1024; k <<= 1) {
    for (int j = k >> 1; j > 0; j >>= 1) {
      int ixj = t ^ j;
      if (ixj > t) {
        bool up = ((t & k) == 0);
        float a = u.tk.sv[t], c = u.tk.sv[ixj];
        if ((a > c) == up) {
          u.tk.sv[t] = c; u.tk.sv[ixj] = a;
          int ti = u.tk.si[t]; u.tk.si[t] = u.tk.si[ixj]; u.tk.si[ixj] = ti;
        }
      }
      __syncthreads();
    }
  }
  if (t >= 1024 - NN) {
    int n = 1023 - t;
    int idx = u.tk.si[t];
    topiL[n] = idx;
    nodeof[b * 1024 + idx] = n;
  }
  __syncthreads();

  // ---- phase F: gather -> normalize -> fn bf16 to global; normL ----
  {
    int n = t >> 3, g = t & 7;
    if (n < NN) {
      int idx = topiL[n];
      const float* xb = x + (size_t)b * CDIM * HWD + idx;
      float vbuf[32];
      float ssl = 0.f;
#pragma unroll
      for (int cc = 0; cc < 32; ++cc) {
        float v = xb[(size_t)(g * 32 + cc) * HWD];
        vbuf[cc] = v;
        ssl += v * v;
      }
      ssl += __shfl_xor(ssl, 1);
      ssl += __shfl_xor(ssl, 2);
      ssl += __shfl_xor(ssl, 4);
      float nrm = sqrtf(ssl);
      float rn = 1.f / fmaxf(nrm, 1e-12f);
      if (g == 0) normL[n] = nrm;
      short* fp = fnG + ((size_t)b * 112 + n) * 256 + g * 32;
#pragma unroll
      for (int cc = 0; cc < 32; cc += 4) {
        short4 s4 = {f2bf(vbuf[cc] * rn), f2bf(vbuf[cc + 1] * rn),
                     f2bf(vbuf[cc + 2] * rn), f2bf(vbuf[cc + 3] * rn)};
        *(short4*)(fp + cc) = s4;
      }
    }
  }
  // zero h0T pad columns (102..135) while fn writes drain
  for (int e = t; e < 64 * 34; e += 1024) {
    int f = e / 34, c = 102 + (e % 34);
    u.m.h0T[f * 136 + c] = 0;
  }
  __syncthreads();   // fn visible (vmcnt drained), pads zeroed

  // ---- phase S: cosine sim via MFMA -> adjPack bits + global adj ----
  for (int tile = wv; tile < 49; tile += 16) {
    int I = tile / 7, J = tile % 7;
    const short* ap = fnG + ((size_t)b * 112 + I * 16 + l16) * 256 + quad * 8;
    const short* bp = fnG + ((size_t)b * 112 + J * 16 + l16) * 256 + quad * 8;
    f32x4 acc = (f32x4){0.f, 0.f, 0.f, 0.f};
#pragma unroll
    for (int kb = 0; kb < 8; ++kb)
      acc = __builtin_amdgcn_mfma_f32_16x16x32_bf16(*(const bf16x8*)(ap + kb * 32),
                                                    *(const bf16x8*)(bp + kb * 32), acc, 0, 0, 0);
#pragma unroll
    for (int r = 0; r < 4; ++r) {
      int i = I * 16 + quad * 4 + r, j = J * 16 + l16;
      bool e = (acc[r] > 0.6f) || (i == j);
      unsigned long long m = __ballot(e);
      if (l16 == 0) {
        int row = I * 16 + quad * 4 + r;
        if (row < NN) adjPack[row][J] = (ushort)((m >> (quad * 16)) & 0xFFFFull);
      }
      if (i < NN && j < NN) adjG[(size_t)b * NN * NN + i * NN + j] = e ? 1 : 0;
    }
  }
  __syncthreads();

  // ---- phase G0: h0 = norm * (fn @ W0) -> h0T bf16 ----
  for (int tile = wv; tile < 28; tile += 16) {
    int mt = tile >> 2, nt = tile & 3;
    const short* ap = fnG + ((size_t)b * 112 + mt * 16 + l16) * 256 + quad * 8;
    const short* bp = w0bT + (nt * 16 + l16) * 256 + quad * 8;
    f32x4 acc = (f32x4){0.f, 0.f, 0.f, 0.f};
#pragma unroll
    for (int kb = 0; kb < 8; ++kb)
      acc = __builtin_amdgcn_mfma_f32_16x16x32_bf16(*(const bf16x8*)(ap + kb * 32),
                                                    *(const bf16x8*)(bp + kb * 32), acc, 0, 0, 0);
    int f = nt * 16 + l16;
#pragma unroll
    for (int r = 0; r < 4; ++r) {
      int node = mt * 16 + quad * 4 + r;
      if (node < NN) u.m.h0T[f * 136 + node] = f2bf(acc[r] * normL[node]);
    }
  }
  __syncthreads();

  for (int layer = 0; layer < 2; ++layer) {
    const float* avs = layer ? g1as : g0as;
    const float* avd = layer ? g1ad : g0ad;
    const float* bias = layer ? g1b : g0b;
    // ---- attention coefficients: asrc/adst per node ----
    {
      int n = t >> 3, g = t & 7;
      if (n < NN) {
        float s1 = 0.f, s2 = 0.f;
#pragma unroll
        for (int uu = 0; uu < 8; ++uu) {
          int f = g * 8 + uu;
          float hv = bf2f(u.m.h0T[f * 136 + n]);
          s1 += hv * avs[f];
          s2 += hv * avd[f];
        }
        s1 += __shfl_xor(s1, 1); s1 += __shfl_xor(s1, 2); s1 += __shfl_xor(s1, 4);
        s2 += __shfl_xor(s2, 1); s2 += __shfl_xor(s2, 2); s2 += __shfl_xor(s2, 4);
        if (g == 0) { asrcL[n] = s1; adstL[n] = s2; }
      }
    }
    __syncthreads();
    // ---- masked softmax rows -> alphaB bf16 ----
    for (int i = wv; i < NN; i += 16) {
      float zi = adstL[i];
      int j1 = 64 + lane;
      bool e0 = (adjPack[i][lane >> 4] >> (lane & 15)) & 1;
      bool e1 = (j1 < NN) && ((adjPack[i][j1 >> 4] >> (j1 & 15)) & 1);
      float p0 = 0.f, p1 = 0.f;
      if (e0) { float z = zi + asrcL[lane]; p0 = __expf(z > 0.f ? z : 0.2f * z); }
      if (e1) { float z = zi + asrcL[j1]; p1 = __expf(z > 0.f ? z : 0.2f * z); }
      float s = p0 + p1;
      s += __shfl_xor(s, 1); s += __shfl_xor(s, 2); s += __shfl_xor(s, 4);
      s += __shfl_xor(s, 8); s += __shfl_xor(s, 16); s += __shfl_xor(s, 32);
      float inv = 1.f / s;
      u.m.alphaB[i * 136 + lane] = f2bf(p0 * inv);
      u.m.alphaB[i * 136 + 64 + lane] = f2bf(p1 * inv);
    }
    __syncthreads();
    // ---- aggregate: g = relu(alphaB @ h0T^T + bias) -> gB ----
    for (int tile = wv; tile < 28; tile += 16) {
      int mt = tile >> 2, nt = tile & 3;
      int ar = mt * 16 + l16; if (ar > NN - 1) ar = NN - 1;
      const short* ap = &u.m.alphaB[ar * 136 + quad * 8];
      const short* bp = &u.m.h0T[(nt * 16 + l16) * 136 + quad * 8];
      f32x4 acc = (f32x4){0.f, 0.f, 0.f, 0.f};
#pragma unroll
      for (int kb = 0; kb < 4; ++kb)
        acc = __builtin_amdgcn_mfma_f32_16x16x32_bf16(*(const bf16x8*)(ap + kb * 32),
                                                      *(const bf16x8*)(bp + kb * 32), acc, 0, 0, 0);
      int f = nt * 16 + l16;
      float bv = bias[f];
#pragma unroll
      for (int r = 0; r < 4; ++r) {
        int i = mt * 16 + quad * 4 + r;
        if (i < NN) u.m.gB[i * 72 + f] = f2bf(fmaxf(acc[r] + bv, 0.f));
      }
    }
    __syncthreads();
    if (layer == 0) {
      // ---- G1: h1 = gB @ W1 -> h0T slot (pads still zero) ----
      for (int tile = wv; tile < 28; tile += 16) {
        int mt = tile >> 2, nt = tile & 3;
        int ar = mt * 16 + l16; if (ar > NN - 1) ar = NN - 1;
        const short* ap = &u.m.gB[ar * 72 + quad * 8];
        const short* bp = w1bT + (nt * 16 + l16) * 64 + quad * 8;
        f32x4 acc = (f32x4){0.f, 0.f, 0.f, 0.f};
#pragma unroll
        for (int kb = 0; kb < 2; ++kb)
          acc = __builtin_amdgcn_mfma_f32_16x16x32_bf16(*(const bf16x8*)(ap + kb * 32),
                                                        *(const bf16x8*)(bp + kb * 32), acc, 0, 0, 0);
        int f = nt * 16 + l16;
#pragma unroll
        for (int r = 0; r < 4; ++r) {
          int node = mt * 16 + quad * 4 + r;
          if (node < NN) u.m.h0T[f * 136 + node] = f2bf(acc[r]);
        }
      }
      __syncthreads();
    }
  }
  // ---- gate: gw = sigmoid(gB @ wg2a^T + b) ----
  float* wgL = (float*)&u.m.alphaB[0];
  if (t < 512) wgL[t] = wg2a[t];
  __syncthreads();
  if (t < NN * NH) {
    int n = t >> 3, h = t & 7;
    float z = bg2a[h];
#pragma unroll
    for (int c = 0; c < GD; ++c) z += bf2f(u.m.gB[n * 72 + c]) * wgL[h * 64 + c];
    gwb[((size_t)b * NN + n) * NH + h] = 1.f / (1.f + __expf(-z));
  }
}

#define FMA16(acc, av, bv)                                                            \
  acc[0][0] += av.x * bv.x; acc[0][1] += av.x * bv.y; acc[0][2] += av.x * bv.z;       \
  acc[0][3] += av.x * bv.w;                                                           \
  acc[1][0] += av.y * bv.x; acc[1][1] += av.y * bv.y; acc[1][2] += av.y * bv.z;       \
  acc[1][3] += av.y * bv.w;                                                           \
  acc[2][0] += av.z * bv.x; acc[2][1] += av.z * bv.y; acc[2][2] += av.z * bv.z;       \
  acc[2][3] += av.z * bv.w;                                                           \
  acc[3][0] += av.w * bv.x; acc[3][1] += av.w * bv.y; acc[3][2] += av.w * bv.z;       \
  acc[3][3] += av.w * bv.w;

// ---------------- QKV GEMM: emits split-bf16 Q/K and V^T bf16 ----------------
__global__ __launch_bounds__(256) void qkv_k(const float* __restrict__ x,
                                             const float* __restrict__ wT,
                                             short* __restrict__ qhp, short* __restrict__ qlp,
                                             short* __restrict__ khp, short* __restrict__ klp,
                                             short* __restrict__ vtp) {
  __shared__ float a_s[16][68];
  __shared__ float b_s[16][68];
  __shared__ float c_s[64][68];
  int m0 = blockIdx.x * 64, n0 = blockIdx.y * 64;
  int b = m0 >> 10, p0 = m0 & 1023;
  int t = threadIdx.x, tx = t & 15, ty = t >> 4;
  float acc[4][4] = {};
  for (int k0 = 0; k0 < 256; k0 += 16) {
    int m = t & 63, kb = t >> 6;
#pragma unroll
    for (int r = 0; r < 4; ++r) {
      int kk = kb * 4 + r;
      a_s[kk][m] = x[((size_t)b * 256 + k0 + kk) * 1024 + p0 + m];
      b_s[kk][m] = wT[(k0 + kk) * 768 + n0 + m];
    }
    __syncthreads();
#pragma unroll
    for (int kk = 0; kk < 16; ++kk) {
      float4 av = *(const float4*)&a_s[kk][ty * 4];
      float4 bv = *(const float4*)&b_s[kk][tx * 4];
      FMA16(acc, av, bv)
    }
    __syncthreads();
  }
  int qi = n0 >> 8;
  if (qi < 2) {
    const float scale = (qi == 0) ? 0.17677669529663687f : 1.f;
    short* hp = (qi == 0) ? qhp : khp;
    short* lp = (qi == 0) ? qlp : klp;
    int n = n0 + tx * 4;
    int hh = (n >> 5) & 7, d = n & 31;
#pragma unroll
    for (int i = 0; i < 4; ++i) {
      int p = p0 + ty * 4 + i;
      size_t e = ((size_t)(b * 8 + hh) * 1024 + p) * 32 + d;
      float v0 = acc[i][0] * scale, v1 = acc[i][1] * scale;
      float v2 = acc[i][2] * scale, v3 = acc[i][3] * scale;
      short4 hi, lo;
      hi.x = f2bf(v0); lo.x = f2bf(v0 - bf2f(hi.x));
      hi.y = f2bf(v1); lo.y = f2bf(v1 - bf2f(hi.y));
      hi.z = f2bf(v2); lo.z = f2bf(v2 - bf2f(hi.z));
      hi.w = f2bf(v3); lo.w = f2bf(v3 - bf2f(hi.w));
      *(short4*)(hp + e) = hi;
      *(short4*)(lp + e) = lo;
    }
  } else {
#pragma unroll
    for (int i = 0; i < 4; ++i)
      *(float4*)&c_s[ty * 4 + i][tx * 4] = *(float4*)&acc[i][0];
    __syncthreads();
    int dl = t >> 2, pg = t & 3;
    int n = n0 + dl;
    int hh = (n >> 5) & 7, d = n & 31;
    size_t rowb = (size_t)(b * 8 + hh) * 32768 + (size_t)d * 1024 + p0;
#pragma unroll
    for (int r = 0; r < 4; ++r) {
      int pl = pg * 16 + r * 4;
      short4 s4;
      s4.x = f2bf(c_s[pl + 0][dl]);
      s4.y = f2bf(c_s[pl + 1][dl]);
      s4.z = f2bf(c_s[pl + 2][dl]);
      s4.w = f2bf(c_s[pl + 3][dl]);
      *(short4*)(vtp + rowb + pl) = s4;
    }
  }
}

// ---------------- flash attention: 16 q-rows/wave, deferred-sum softmax ----------------
__global__ __launch_bounds__(256, 4) void attn_k(const short* __restrict__ qh,
                                                 const short* __restrict__ ql,
                                                 const short* __restrict__ kh,
                                                 const short* __restrict__ kl,
                                                 const short* __restrict__ vt,
                                                 const int* __restrict__ nodeof,
                                                 const float* __restrict__ gw,
                                                 const unsigned char* __restrict__ adj,
                                                 float* __restrict__ ao) {
  __shared__ __align__(16) short p_s[4][16 * 72];
  __shared__ float aw_s[4][16];
  int t = threadIdx.x;
  int wid = t >> 6, lane = t & 63, quad = lane >> 4, l16 = lane & 15;
  int bh = blockIdx.y, b = bh >> 3, h = bh & 7;
  int q0 = blockIdx.x * 64 + wid * 16;
  size_t base = (size_t)bh * 32768;
  short* pw = &p_s[wid][0];
  float* aw = &aw_s[wid][0];

  size_t qoff = base + (size_t)(q0 + l16) * 32 + quad * 8;
  bf16x8 qhf = *(const bf16x8*)(qh + qoff);
  bf16x8 qlf = *(const bf16x8*)(ql + qoff);

  int irow[4]; float grq[4];
#pragma unroll
  for (int r = 0; r < 4; ++r) {
    int qr = q0 + quad * 4 + r;
    int in_ = nodeof[b * 1024 + qr];
    irow[r] = in_;
    grq[r] = (in_ >= 0) ? gw[((size_t)b * NN + in_) * NH + h] : 0.f;
  }
  const unsigned char* adjB = adj + (size_t)b * NN * NN;

  f32x4 ot[2];
  ot[0] = (f32x4){0.f, 0.f, 0.f, 0.f};
  ot[1] = (f32x4){0.f, 0.f, 0.f, 0.f};
  float l_r[4] = {0.f, 0.f, 0.f, 0.f};

  for (int ch = 0; ch < 16; ++ch) {
    int c0 = ch * 64;
    bf16x8 khf[4], klf[4];
#pragma unroll
    for (int ni = 0; ni < 4; ++ni) {
      size_t off = base + (size_t)(c0 + ni * 16 + l16) * 32 + quad * 8;
      khf[ni] = *(const bf16x8*)(kh + off);
      klf[ni] = *(const bf16x8*)(kl + off);
    }
    bf16x8 vaf[2][2];
#pragma unroll
    for (int mi = 0; mi < 2; ++mi)
#pragma unroll
      for (int ks = 0; ks < 2; ++ks)
        vaf[mi][ks] = *(const bf16x8*)(vt + base + (size_t)(mi * 16 + l16) * 1024 +
                                       c0 + ks * 32 + quad * 8);
    int jn[4]; float gcn[4];
#pragma unroll
    for (int ni = 0; ni < 4; ++ni) {
      int j = nodeof[b * 1024 + c0 + ni * 16 + l16];
      jn[ni] = j;
      gcn[ni] = (j >= 0) ? gw[((size_t)b * NN + j) * NH + h] : 0.f;
    }
    f32x4 s[4];
#pragma unroll
    for (int ni = 0; ni < 4; ++ni) {
      f32x4 a = (f32x4){0.f, 0.f, 0.f, 0.f};
      a = __builtin_amdgcn_mfma_f32_16x16x32_bf16(qhf, khf[ni], a, 0, 0, 0);
      a = __builtin_amdgcn_mfma_f32_16x16x32_bf16(qhf, klf[ni], a, 0, 0, 0);
      a = __builtin_amdgcn_mfma_f32_16x16x32_bf16(qlf, khf[ni], a, 0, 0, 0);
      s[ni] = a;
    }
#pragma unroll
    for (int r = 0; r < 4; ++r) {
      int in_ = irow[r];
      if (in_ >= 0) {
        const unsigned char* ar = adjB + (size_t)in_ * NN;
        float g = grq[r];
#pragma unroll
        for (int ni = 0; ni < 4; ++ni)
          if (jn[ni] >= 0 && ar[jn[ni]]) s[ni][r] += g * gcn[ni];
      }
    }
#pragma unroll
    for (int r = 0; r < 4; ++r) {
      float e0 = __expf(s[0][r]);
      float e1 = __expf(s[1][r]);
      float e2 = __expf(s[2][r]);
      float e3 = __expf(s[3][r]);
      l_r[r] += (e0 + e1) + (e2 + e3);
      int prow = (quad * 4 + r) * 72;
      pw[prow + 0 + l16] = f2bf(e0);
      pw[prow + 16 + l16] = f2bf(e1);
      pw[prow + 32 + l16] = f2bf(e2);
      pw[prow + 48 + l16] = f2bf(e3);
    }
#pragma unroll
    for (int ks = 0; ks < 2; ++ks) {
      bf16x8 pb = *(const bf16x8*)(pw + l16 * 72 + ks * 32 + quad * 8);
      ot[0] = __builtin_amdgcn_mfma_f32_16x16x32_bf16(vaf[0][ks], pb, ot[0], 0, 0, 0);
      ot[1] = __builtin_amdgcn_mfma_f32_16x16x32_bf16(vaf[1][ks], pb, ot[1], 0, 0, 0);
    }
  }
#pragma unroll
  for (int r = 0; r < 4; ++r) {
    float ls = l_r[r];
    ls += __shfl_xor(ls, 1);
    ls += __shfl_xor(ls, 2);
    ls += __shfl_xor(ls, 4);
    ls += __shfl_xor(ls, 8);
    if (l16 == 0) aw[quad * 4 + r] = 1.f / ls;
  }
  float li = aw[l16];
  ot[0] *= li;
  ot[1] *= li;
  float* os = (float*)pw;
#pragma unroll
  for (int mi = 0; mi < 2; ++mi)
#pragma unroll
    for (int r = 0; r < 4; ++r)
      os[l16 * 36 + mi * 16 + quad * 4 + r] = ot[mi][r];
  int qr2 = lane >> 2, dg = (lane & 3) * 8;
  size_t ob = (size_t)(b * 1024 + q0 + qr2) * 256 + h * 32 + dg;
  *(float4*)&ao[ob] = *(float4*)&os[qr2 * 36 + dg];
  *(float4*)&ao[ob + 4] = *(float4*)&os[qr2 * 36 + dg + 4];
}

// ---------------- proj GEMM + bias + transposed store ----------------
__global__ __launch_bounds__(256) void proj_k(const float* __restrict__ ao,
                                              const float* __restrict__ wT,
                                              const float* __restrict__ bias,
                                              float* __restrict__ out) {
  __shared__ float a_s[16][68];
  __shared__ float b_s[16][68];
  __shared__ float c_s[64][68];
  int m0 = blockIdx.x * 64, n0 = blockIdx.y * 64;
  int b = m0 >> 10, p0 = m0 & 1023;
  int t = threadIdx.x, tx = t & 15, ty = t >> 4;
  float acc[4][4] = {};
  for (int k0 = 0; k0 < 256; k0 += 16) {
    {
      int kk = t & 15, mm = t >> 4;
#pragma unroll
      for (int r = 0; r < 4; ++r) {
        int m = mm + r * 16;
        a_s[kk][m] = ao[(size_t)(m0 + m) * 256 + k0 + kk];
      }
      int mB = t & 63, kb = t >> 6;
#pragma unroll
      for (int r2 = 0; r2 < 4; ++r2) {
        int kk2 = kb * 4 + r2;
        b_s[kk2][mB] = wT[(k0 + kk2) * 256 + n0 + mB];
      }
    }
    __syncthreads();
#pragma unroll
    for (int kk = 0; kk < 16; ++kk) {
      float4 av = *(const float4*)&a_s[kk][ty * 4];
      float4 bv = *(const float4*)&b_s[kk][tx * 4];
      FMA16(acc, av, bv)
    }
    __syncthreads();
  }
#pragma unroll
  for (int i = 0; i < 4; ++i)
#pragma unroll
    for (int j = 0; j < 4; ++j) c_s[tx * 4 + j][ty * 4 + i] = acc[i][j];
  __syncthreads();
  {
    int cl = t >> 2, pg = t & 3;
    float bv = bias[n0 + cl];
#pragma unroll
    for (int r = 0; r < 4; ++r) {
      int p = pg * 16 + r * 4;
      float4 v4 = {c_s[cl][p] + bv, c_s[cl][p + 1] + bv, c_s[cl][p + 2] + bv, c_s[cl][p + 3] + bv};
      *(float4*)&out[((size_t)b * 256 + n0 + cl) * 1024 + p0 + p] = v4;
    }
  }
}

extern "C" void kernel_launch(void* const* d_in, const int* in_sizes, int n_in,
                              void* d_out, int out_size, void* d_ws, size_t ws_size,
                              hipStream_t stream) {
  const float* x      = (const float*)d_in[0];
  const float* w_qkv  = (const float*)d_in[1];
  const float* w_proj = (const float*)d_in[2];
  const float* b_proj = (const float*)d_in[3];
  const float* g0W    = (const float*)d_in[4];
  const float* g0as   = (const float*)d_in[5];
  const float* g0ad   = (const float*)d_in[6];
  const float* g0b    = (const float*)d_in[7];
  const float* g1W    = (const float*)d_in[8];
  const float* g1as   = (const float*)d_in[9];
  const float* g1ad   = (const float*)d_in[10];
  const float* g1b    = (const float*)d_in[11];
  const float* wg2a   = (const float*)d_in[12];
  const float* bg2a   = (const float*)d_in[13];
  float* out = (float*)d_out;
  float* ws = (float*)d_ws;

  size_t o = 0;
  auto alloc = [&](size_t nf) { float* p = ws + o; o += (nf + 15) & ~(size_t)15; return p; };
  float* wqkvT  = alloc(256 * 768);
  float* wprojT = alloc(256 * 256);
  float* imp    = alloc(8 * 1024);
  int*   nodeof = (int*)alloc(8 * 1024);
  short* fnG    = (short*)alloc(8 * 112 * 256 / 2);
  short* w0bT   = (short*)alloc(256 * 64 / 2);
  short* w1bT   = (short*)alloc(64 * 64 / 2);
  unsigned char* adj = (unsigned char*)alloc((8 * NN * NN + 3) / 4 + 16);
  float* gwb    = alloc(8 * NN * 8);
  short* qh     = (short*)alloc(1048576);
  short* ql     = (short*)alloc(1048576);
  short* kh     = (short*)alloc(1048576);
  short* kl     = (short*)alloc(1048576);
  short* vt     = (short*)alloc(1048576);
  float* ao     = alloc((size_t)8 * 1024 * 256);
  if (ws_size < o * sizeof(float)) return;

  transpose_k<<<dim3(8, 24), dim3(32, 8), 0, stream>>>(w_qkv, wqkvT, 768, 256);
  transpose_k<<<dim3(8, 8), dim3(32, 8), 0, stream>>>(w_proj, wprojT, 256, 256);
  prep_k<<<80, 256, 0, stream>>>(g0W, g1W, w0bT, w1bT);
  importance_k<<<256, 256, 0, stream>>>(x, imp);
  graph_k<<<8, 1024, 0, stream>>>(x, imp, w0bT, w1bT, g0as, g0ad, g0b,
                                  g1as, g1ad, g1b, wg2a, bg2a,
                                  nodeof, fnG, adj, gwb);
  qkv_k<<<dim3(128, 12), 256, 0, stream>>>(x, wqkvT, qh, ql, kh, kl, vt);
  attn_k<<<dim3(16, 64), 256, 0, stream>>>(qh, ql, kh, kl, vt, nodeof, gwb, adj, ao);
  proj_k<<<dim3(128, 4), 256, 0, stream>>>(ao, wprojT, b_proj, out);
}